// Round 1
// 139.946 us; speedup vs baseline: 1.0281x; 1.0281x over previous
//
#include <hip/hip_runtime.h>

// Problem constants (from reference)
#define BB 1024
#define SS 200
#define PQ_M 8
#define VALS 256
#define SUB_DIM 16
#define N_TOKENS (BB * SS)             // 204800
#define OUT_PER_TOKEN (PQ_M * SUB_DIM) // 128 floats = 512 B

typedef float f32x4 __attribute__((ext_vector_type(4)));
typedef int   i32x4 __attribute__((ext_vector_type(4)));

// ---------------------------------------------------------------------------
// Pass 1: pure random gather. One thread per (token, half). Dependent chain:
// ids[tok] -> codes int4 (16B of the token's 32B code row) -> pack 4 bytes
// -> coalesced u32 store into the 1.6MB packed buffer. 409600 threads,
// 6400 waves => ~25 waves/CU, each with one chain in flight: thousands of
// random lines outstanding per CU, far beyond Little's-law needs.
// ---------------------------------------------------------------------------
__global__ __launch_bounds__(256) void gather_codes_kernel(
    const int*    __restrict__ ids,      // [N_TOKENS]
    const i32x4*  __restrict__ codes4,   // item_codes viewed as int4 pairs
    unsigned int* __restrict__ packed)   // [N_TOKENS*2] u32 (8 packed bytes/token)
{
    const int gid  = blockIdx.x * blockDim.x + threadIdx.x;
    const int half = gid & 1;            // which 4 of the 8 codes
    const int tok  = gid >> 1;

    const int id = ids[tok];             // 2 adjacent lanes share -> merged
    const i32x4 c = codes4[(size_t)id * 2 + half];  // random 16B gather

    const unsigned int p = (unsigned int)(c.x & 255)
                         | ((unsigned int)(c.y & 255) << 8)
                         | ((unsigned int)(c.z & 255) << 16)
                         | ((unsigned int)(c.w & 255) << 24);
    packed[gid] = p;                     // wave: 256B contiguous
}

// ---------------------------------------------------------------------------
// Pass 2: pure streamer. 32 threads per token (t = lane-in-token), 4 tokens
// per thread with independent chains. Chain depth is now 1 short broadcast
// load (8B packed codes, L3-hot) + 1 centroid read (128KB L2-hot table,
// each 4-lane quad reads one contiguous 64B line). Stores: nontemporal,
// 1KB contiguous per wave per j -> should run at the write-BW ceiling.
// ---------------------------------------------------------------------------
#define T_PER_THREAD 4
#define TOK_SLICE (N_TOKENS / T_PER_THREAD)  // 51200

__global__ __launch_bounds__(256) void expand_kernel(
    const unsigned long long* __restrict__ packed,  // [N_TOKENS] 8B codes
    const f32x4* __restrict__ cent4,                // [PQ_M*VALS*4] float4
    float*       __restrict__ out)                  // [N_TOKENS * 128]
{
    const int gid  = blockIdx.x * blockDim.x + threadIdx.x;
    const int t    = gid & 31;          // float4 slot within token
    const int slot = gid >> 5;
    const int m    = t >> 2;            // PQ dim 0..7
    const int c4   = t & 3;             // float4 chunk within sub-vector

    // Stage 1: 4 independent 8B broadcast loads (all 32 lanes same address)
    unsigned long long p[T_PER_THREAD];
#pragma unroll
    for (int j = 0; j < T_PER_THREAD; ++j)
        p[j] = packed[slot + j * TOK_SLICE];

    // Stage 2: byte-extract + centroid float4 reads (hot 128KB table)
    f32x4 v[T_PER_THREAD];
#pragma unroll
    for (int j = 0; j < T_PER_THREAD; ++j) {
        const int code = (int)((p[j] >> (8 * m)) & 255ULL);
        v[j] = cent4[(m * VALS + code) * (SUB_DIM / 4) + c4];
    }

    // Stage 3: nontemporal coalesced stores (1KB contiguous per wave per j)
#pragma unroll
    for (int j = 0; j < T_PER_THREAD; ++j) {
        f32x4* dst = (f32x4*)(out + (size_t)(slot + j * TOK_SLICE) * OUT_PER_TOKEN);
        __builtin_nontemporal_store(v[j], dst + t);
    }
}

// ---------------------------------------------------------------------------
// Fallback: previous fused single-pass kernel (used only if the workspace is
// too small for the 1.6MB packed-code buffer).
// ---------------------------------------------------------------------------
__global__ __launch_bounds__(256) void pq_gather_kernel(
    const int*   __restrict__ ids,
    const int*   __restrict__ codes,
    const float* __restrict__ cent,
    float*       __restrict__ out)
{
    const int gid  = blockIdx.x * blockDim.x + threadIdx.x;
    const int t    = gid & 31;
    const int slot = gid >> 5;
    const int m    = t >> 2;
    const int c4   = t & 3;

    int tok[T_PER_THREAD];
#pragma unroll
    for (int j = 0; j < T_PER_THREAD; ++j)
        tok[j] = slot + j * TOK_SLICE;

    int id[T_PER_THREAD];
#pragma unroll
    for (int j = 0; j < T_PER_THREAD; ++j)
        id[j] = ids[tok[j]];

    int code[T_PER_THREAD];
#pragma unroll
    for (int j = 0; j < T_PER_THREAD; ++j)
        code[j] = codes[id[j] * PQ_M + m];

    float4 v[T_PER_THREAD];
    const float4* cent4 = (const float4*)cent;
#pragma unroll
    for (int j = 0; j < T_PER_THREAD; ++j)
        v[j] = cent4[(m * VALS + code[j]) * (SUB_DIM / 4) + c4];

#pragma unroll
    for (int j = 0; j < T_PER_THREAD; ++j)
        ((float4*)(out + (size_t)tok[j] * OUT_PER_TOKEN))[t] = v[j];
}

extern "C" void kernel_launch(void* const* d_in, const int* in_sizes, int n_in,
                              void* d_out, int out_size, void* d_ws, size_t ws_size,
                              hipStream_t stream)
{
    const int*   ids   = (const int*)d_in[0];    // input_ids [1024,200]
    const int*   codes = (const int*)d_in[1];    // item_codes [1000002,8]
    const float* cent  = (const float*)d_in[2];  // centroids [8,256,16] fp32
    float*       out   = (float*)d_out;          // [1024,200,128] fp32

    const size_t packed_bytes = (size_t)N_TOKENS * 8;  // 1.6 MB

    if (d_ws != nullptr && ws_size >= packed_bytes) {
        unsigned int* packed = (unsigned int*)d_ws;

        // Pass 1: 409600 threads -> 1600 blocks
        gather_codes_kernel<<<(N_TOKENS * 2) / 256, 256, 0, stream>>>(
            ids, (const i32x4*)codes, packed);

        // Pass 2: 1,638,400 threads -> 6400 blocks
        expand_kernel<<<(N_TOKENS / T_PER_THREAD) * 32 / 256, 256, 0, stream>>>(
            (const unsigned long long*)packed, (const f32x4*)cent, out);
    } else {
        const int total_threads = (N_TOKENS / T_PER_THREAD) * 32;
        pq_gather_kernel<<<total_threads / 256, 256, 0, stream>>>(
            ids, codes, cent, out);
    }
}